// Round 1
// baseline (322.662 us; speedup 1.0000x reference)
//
#include <hip/hip_runtime.h>
#include <hip/hip_bf16.h>
#include <math.h>

#define BATCH 4096
#define SEQ 200
#define EMB 512

// ---------------------------------------------------------------------------
// Kernel 1: embedding bag (gather + mean over SEQ)
// One block per batch row. 256 threads: threads [0,128) handle even seq
// positions, [128,256) odd. Each thread accumulates one float4 (4 of the 512
// columns). Row reads are fully coalesced: 128 lanes x 16B = 2048B per row.
// ---------------------------------------------------------------------------
__global__ __launch_bounds__(256) void embed_mean_kernel(
    const int* __restrict__ idx, const float* __restrict__ E,
    float* __restrict__ sent)
{
    __shared__ int sIdx[SEQ];
    __shared__ float4 red[128];
    const int b = blockIdx.x;
    const int t = threadIdx.x;
    if (t < SEQ) sIdx[t] = idx[b * SEQ + t];
    __syncthreads();

    const int half = t >> 7;   // 0 or 1
    const int lane = t & 127;  // column group (float4 index)
    float4 acc = make_float4(0.f, 0.f, 0.f, 0.f);
    for (int s = half; s < SEQ; s += 2) {
        const float4* row =
            reinterpret_cast<const float4*>(E + (size_t)sIdx[s] * EMB);
        float4 v = row[lane];
        acc.x += v.x; acc.y += v.y; acc.z += v.z; acc.w += v.w;
    }
    if (half == 1) red[lane] = acc;
    __syncthreads();
    if (half == 0) {
        float4 o = red[lane];
        const float sc = 1.0f / (float)SEQ;
        float4 r;
        r.x = (acc.x + o.x) * sc;
        r.y = (acc.y + o.y) * sc;
        r.z = (acc.z + o.z) * sc;
        r.w = (acc.w + o.w) * sc;
        reinterpret_cast<float4*>(sent + (size_t)b * EMB)[lane] = r;
    }
}

// ---------------------------------------------------------------------------
// Kernel 2: fp32 tiled GEMM, C = relu(A @ W + bias)
// A: [M x K] row-major, W: [K x N] row-major, C: [M x N].
// 64x64 tile per block, BK=16, 256 threads, 4x4 micro-tile per thread.
// ---------------------------------------------------------------------------
template <int N, int K>
__global__ __launch_bounds__(256) void gemm_bias_relu(
    const float* __restrict__ A, const float* __restrict__ W,
    const float* __restrict__ bias, float* __restrict__ C)
{
    constexpr int BM = 64, BN = 64, BK = 16, LDT = 68;  // +4 pad keeps 16B align
    __shared__ float As[BK][LDT];  // transposed A tile: As[k][m]
    __shared__ float Bs[BK][LDT];  // Bs[k][n]

    const int t = threadIdx.x;
    const int m0 = blockIdx.x * BM;
    const int n0 = blockIdx.y * BN;

    // global staging assignments
    const int arow = t >> 2;          // 0..63  (tile row of A)
    const int acg  = (t & 3) * 4;     // 0,4,8,12 (k-subgroup of A)
    const int brow = t >> 4;          // 0..15  (k row of W)
    const int bcg  = (t & 15) * 4;    // 0..60  (col group of W)

    // compute assignments: 4 rows x 4 cols per thread
    const int tr = (t >> 4) * 4;      // tile row base
    const int tc = (t & 15) * 4;      // tile col base

    float acc[4][4] = {};

    for (int kt = 0; kt < K; kt += BK) {
        float4 av = *reinterpret_cast<const float4*>(
            &A[(size_t)(m0 + arow) * K + kt + acg]);
        float4 bv = *reinterpret_cast<const float4*>(
            &W[(size_t)(kt + brow) * N + n0 + bcg]);
        __syncthreads();  // previous compute done before overwriting LDS
        As[acg + 0][arow] = av.x;
        As[acg + 1][arow] = av.y;
        As[acg + 2][arow] = av.z;
        As[acg + 3][arow] = av.w;
        *reinterpret_cast<float4*>(&Bs[brow][bcg]) = bv;
        __syncthreads();
#pragma unroll
        for (int kk = 0; kk < BK; ++kk) {
            float4 a4 = *reinterpret_cast<const float4*>(&As[kk][tr]);
            float4 b4 = *reinterpret_cast<const float4*>(&Bs[kk][tc]);
            float aa[4] = {a4.x, a4.y, a4.z, a4.w};
            float bb[4] = {b4.x, b4.y, b4.z, b4.w};
#pragma unroll
            for (int i = 0; i < 4; ++i)
#pragma unroll
                for (int j = 0; j < 4; ++j)
                    acc[i][j] = fmaf(aa[i], bb[j], acc[i][j]);
        }
    }

    float4 bias4 = *reinterpret_cast<const float4*>(&bias[n0 + tc]);
    float bb[4] = {bias4.x, bias4.y, bias4.z, bias4.w};
#pragma unroll
    for (int i = 0; i < 4; ++i) {
        float4 r;
        r.x = fmaxf(acc[i][0] + bb[0], 0.f);
        r.y = fmaxf(acc[i][1] + bb[1], 0.f);
        r.z = fmaxf(acc[i][2] + bb[2], 0.f);
        r.w = fmaxf(acc[i][3] + bb[3], 0.f);
        *reinterpret_cast<float4*>(&C[(size_t)(m0 + tr + i) * N + n0 + tc]) = r;
    }
}

// ---------------------------------------------------------------------------
// Kernel 3: final layer (K=64, N=3) + softmax. One thread per batch row.
// ---------------------------------------------------------------------------
__global__ __launch_bounds__(256) void final_softmax_kernel(
    const float* __restrict__ h4, const float* __restrict__ W5,
    const float* __restrict__ b5, float* __restrict__ out)
{
    __shared__ float w[64 * 3];
    __shared__ float bb[3];
    const int t = threadIdx.x;
    if (t < 192) w[t] = W5[t];
    if (t < 3) bb[t] = b5[t];
    __syncthreads();

    const int row = blockIdx.x * 256 + t;
    float a0 = bb[0], a1 = bb[1], a2 = bb[2];
    const float* hr = h4 + (size_t)row * 64;
#pragma unroll
    for (int k = 0; k < 64; ++k) {
        float h = hr[k];
        a0 = fmaf(h, w[k * 3 + 0], a0);
        a1 = fmaf(h, w[k * 3 + 1], a1);
        a2 = fmaf(h, w[k * 3 + 2], a2);
    }
    float m  = fmaxf(a0, fmaxf(a1, a2));
    float e0 = expf(a0 - m), e1 = expf(a1 - m), e2 = expf(a2 - m);
    float inv = 1.0f / (e0 + e1 + e2);
    out[row * 3 + 0] = e0 * inv;
    out[row * 3 + 1] = e1 * inv;
    out[row * 3 + 2] = e2 * inv;
}

// ---------------------------------------------------------------------------
// Launch. setup_inputs dict order:
//   0: inputs (int32 [4096,200])   1: E (f32 [100000,512])
//   2: W1 3: b1 4: W2 5: b2 6: W3 7: b3 8: W4 9: b4 10: W5 11: b5
// Workspace layout (floats), ping-pong so peak = 16 MB:
//   sent @ 0         (2,097,152)   h1 @ 2,097,152 (2,097,152)
//   h2   @ 0         (1,048,576)   h3 @ 2,097,152 (  524,288)
//   h4   @ 0         (  262,144)
// ---------------------------------------------------------------------------
extern "C" void kernel_launch(void* const* d_in, const int* in_sizes, int n_in,
                              void* d_out, int out_size, void* d_ws,
                              size_t ws_size, hipStream_t stream)
{
    const int*   inputs = (const int*)d_in[0];
    const float* E  = (const float*)d_in[1];
    const float* W1 = (const float*)d_in[2];
    const float* b1 = (const float*)d_in[3];
    const float* W2 = (const float*)d_in[4];
    const float* b2 = (const float*)d_in[5];
    const float* W3 = (const float*)d_in[6];
    const float* b3 = (const float*)d_in[7];
    const float* W4 = (const float*)d_in[8];
    const float* b4 = (const float*)d_in[9];
    const float* W5 = (const float*)d_in[10];
    const float* b5 = (const float*)d_in[11];

    float* ws   = (float*)d_ws;
    float* sent = ws;                // 8 MB
    float* h1   = ws + 2097152;      // 8 MB
    float* h2   = ws;                // 4 MB (sent dead)
    float* h3   = ws + 2097152;      // 2 MB (h1 dead)
    float* h4   = ws;                // 1 MB (h2 dead)
    float* out  = (float*)d_out;

    embed_mean_kernel<<<BATCH, 256, 0, stream>>>(inputs, E, sent);
    gemm_bias_relu<512, 512><<<dim3(BATCH / 64, 512 / 64), 256, 0, stream>>>(
        sent, W1, b1, h1);
    gemm_bias_relu<256, 512><<<dim3(BATCH / 64, 256 / 64), 256, 0, stream>>>(
        h1, W2, b2, h2);
    gemm_bias_relu<128, 256><<<dim3(BATCH / 64, 128 / 64), 256, 0, stream>>>(
        h2, W3, b3, h3);
    gemm_bias_relu<64, 128><<<dim3(BATCH / 64, 64 / 64), 256, 0, stream>>>(
        h3, W4, b4, h4);
    final_softmax_kernel<<<BATCH / 256, 256, 0, stream>>>(h4, W5, b5, out);
}

// Round 2
// 272.837 us; speedup vs baseline: 1.1826x; 1.1826x over previous
//
#include <hip/hip_runtime.h>
#include <hip/hip_bf16.h>
#include <math.h>

#define BATCH 4096
#define SEQ 200
#define EMB 512
#define VOCAB 100000

// ---------------------------------------------------------------------------
// bf16 helpers (RNE float->bf16; cheap bf16->float via bit ops)
// ---------------------------------------------------------------------------
__device__ inline unsigned int f2bf(float f) {
    unsigned int u = __float_as_uint(f);
    return (u + 0x7FFFu + ((u >> 16) & 1u)) >> 16;
}
__device__ inline unsigned int pack2(float lo, float hi) {
    return f2bf(lo) | (f2bf(hi) << 16);
}
__device__ inline float bflo(unsigned int u) { return __uint_as_float(u << 16); }
__device__ inline float bfhi(unsigned int u) { return __uint_as_float(u & 0xFFFF0000u); }

// ---------------------------------------------------------------------------
// Kernel 0: convert E (fp32 [VOCAB x EMB]) to bf16 table in workspace.
// Each thread converts 8 floats -> 16B of bf16 per iteration.
// ---------------------------------------------------------------------------
__global__ __launch_bounds__(256) void convert_E_bf16(
    const float* __restrict__ E, unsigned int* __restrict__ Eb4, int n8)
{
    const int stride = gridDim.x * 256;
    for (int i = blockIdx.x * 256 + threadIdx.x; i < n8; i += stride) {
        const float4* p = reinterpret_cast<const float4*>(E) + (size_t)i * 2;
        float4 a = p[0], b = p[1];
        uint4 o;
        o.x = pack2(a.x, a.y);
        o.y = pack2(a.z, a.w);
        o.z = pack2(b.x, b.y);
        o.w = pack2(b.z, b.w);
        reinterpret_cast<uint4*>(Eb4)[i] = o;
    }
}

// ---------------------------------------------------------------------------
// Kernel 1a: embedding bag from bf16 table. One block per batch row,
// 256 threads = 4 waves. Each wave reads whole 1KB rows (64 lanes x 16B),
// waves split the 200 seq positions 4 ways; fp32 accumulate; LDS reduce.
// ---------------------------------------------------------------------------
__global__ __launch_bounds__(256) void embed_mean_bf16(
    const int* __restrict__ idx, const unsigned int* __restrict__ Eb,
    float* __restrict__ sent)
{
    __shared__ int sIdx[SEQ];
    __shared__ float red[3 * 512];
    const int b = blockIdx.x;
    const int t = threadIdx.x;
    if (t < SEQ) sIdx[t] = idx[b * SEQ + t];
    __syncthreads();

    const int g = t >> 6;      // wave id 0..3
    const int lane = t & 63;   // 16B chunk within row
    float acc[8] = {};
    for (int s = g; s < SEQ; s += 4) {
        const uint4* row =
            reinterpret_cast<const uint4*>(Eb + (size_t)sIdx[s] * (EMB / 2));
        uint4 v = row[lane];
        acc[0] += bflo(v.x); acc[1] += bfhi(v.x);
        acc[2] += bflo(v.y); acc[3] += bfhi(v.y);
        acc[4] += bflo(v.z); acc[5] += bfhi(v.z);
        acc[6] += bflo(v.w); acc[7] += bfhi(v.w);
    }
    if (g) {
        float4* r = reinterpret_cast<float4*>(&red[(g - 1) * 512 + lane * 8]);
        r[0] = make_float4(acc[0], acc[1], acc[2], acc[3]);
        r[1] = make_float4(acc[4], acc[5], acc[6], acc[7]);
    }
    __syncthreads();
    if (g == 0) {
        const float sc = 1.0f / (float)SEQ;
        float o[8];
#pragma unroll
        for (int j = 0; j < 8; ++j)
            o[j] = (acc[j] + red[0 * 512 + lane * 8 + j] +
                    red[1 * 512 + lane * 8 + j] + red[2 * 512 + lane * 8 + j]) * sc;
        float4* dst = reinterpret_cast<float4*>(sent + (size_t)b * EMB + lane * 8);
        dst[0] = make_float4(o[0], o[1], o[2], o[3]);
        dst[1] = make_float4(o[4], o[5], o[6], o[7]);
    }
}

// ---------------------------------------------------------------------------
// Kernel 1b (fallback, fp32 gather) — used only if ws_size is too small for
// the bf16 table.
// ---------------------------------------------------------------------------
__global__ __launch_bounds__(256) void embed_mean_kernel(
    const int* __restrict__ idx, const float* __restrict__ E,
    float* __restrict__ sent)
{
    __shared__ int sIdx[SEQ];
    __shared__ float4 red[128];
    const int b = blockIdx.x;
    const int t = threadIdx.x;
    if (t < SEQ) sIdx[t] = idx[b * SEQ + t];
    __syncthreads();

    const int half = t >> 7;
    const int lane = t & 127;
    float4 acc = make_float4(0.f, 0.f, 0.f, 0.f);
    for (int s = half; s < SEQ; s += 2) {
        const float4* row =
            reinterpret_cast<const float4*>(E + (size_t)sIdx[s] * EMB);
        float4 v = row[lane];
        acc.x += v.x; acc.y += v.y; acc.z += v.z; acc.w += v.w;
    }
    if (half == 1) red[lane] = acc;
    __syncthreads();
    if (half == 0) {
        float4 o = red[lane];
        const float sc = 1.0f / (float)SEQ;
        float4 r;
        r.x = (acc.x + o.x) * sc;
        r.y = (acc.y + o.y) * sc;
        r.z = (acc.z + o.z) * sc;
        r.w = (acc.w + o.w) * sc;
        reinterpret_cast<float4*>(sent + (size_t)b * EMB)[lane] = r;
    }
}

// ---------------------------------------------------------------------------
// Kernel 2: fp32 tiled GEMM, C = relu(A @ W + bias)
// 64x64 tile per block, BK=16, 256 threads, 4x4 micro-tile per thread.
// ---------------------------------------------------------------------------
template <int N, int K>
__global__ __launch_bounds__(256) void gemm_bias_relu(
    const float* __restrict__ A, const float* __restrict__ W,
    const float* __restrict__ bias, float* __restrict__ C)
{
    constexpr int BM = 64, BN = 64, BK = 16, LDT = 68;
    __shared__ float As[BK][LDT];
    __shared__ float Bs[BK][LDT];

    const int t = threadIdx.x;
    const int m0 = blockIdx.x * BM;
    const int n0 = blockIdx.y * BN;

    const int arow = t >> 2;
    const int acg  = (t & 3) * 4;
    const int brow = t >> 4;
    const int bcg  = (t & 15) * 4;

    const int tr = (t >> 4) * 4;
    const int tc = (t & 15) * 4;

    float acc[4][4] = {};

    for (int kt = 0; kt < K; kt += BK) {
        float4 av = *reinterpret_cast<const float4*>(
            &A[(size_t)(m0 + arow) * K + kt + acg]);
        float4 bv = *reinterpret_cast<const float4*>(
            &W[(size_t)(kt + brow) * N + n0 + bcg]);
        __syncthreads();
        As[acg + 0][arow] = av.x;
        As[acg + 1][arow] = av.y;
        As[acg + 2][arow] = av.z;
        As[acg + 3][arow] = av.w;
        *reinterpret_cast<float4*>(&Bs[brow][bcg]) = bv;
        __syncthreads();
#pragma unroll
        for (int kk = 0; kk < BK; ++kk) {
            float4 a4 = *reinterpret_cast<const float4*>(&As[kk][tr]);
            float4 b4 = *reinterpret_cast<const float4*>(&Bs[kk][tc]);
            float aa[4] = {a4.x, a4.y, a4.z, a4.w};
            float bb[4] = {b4.x, b4.y, b4.z, b4.w};
#pragma unroll
            for (int i = 0; i < 4; ++i)
#pragma unroll
                for (int j = 0; j < 4; ++j)
                    acc[i][j] = fmaf(aa[i], bb[j], acc[i][j]);
        }
    }

    float4 bias4 = *reinterpret_cast<const float4*>(&bias[n0 + tc]);
    float bb[4] = {bias4.x, bias4.y, bias4.z, bias4.w};
#pragma unroll
    for (int i = 0; i < 4; ++i) {
        float4 r;
        r.x = fmaxf(acc[i][0] + bb[0], 0.f);
        r.y = fmaxf(acc[i][1] + bb[1], 0.f);
        r.z = fmaxf(acc[i][2] + bb[2], 0.f);
        r.w = fmaxf(acc[i][3] + bb[3], 0.f);
        *reinterpret_cast<float4*>(&C[(size_t)(m0 + tr + i) * N + n0 + tc]) = r;
    }
}

// ---------------------------------------------------------------------------
// Kernel 3: final layer (K=64, N=3) + softmax. One thread per batch row.
// ---------------------------------------------------------------------------
__global__ __launch_bounds__(256) void final_softmax_kernel(
    const float* __restrict__ h4, const float* __restrict__ W5,
    const float* __restrict__ b5, float* __restrict__ out)
{
    __shared__ float w[64 * 3];
    __shared__ float bb[3];
    const int t = threadIdx.x;
    if (t < 192) w[t] = W5[t];
    if (t < 3) bb[t] = b5[t];
    __syncthreads();

    const int row = blockIdx.x * 256 + t;
    float a0 = bb[0], a1 = bb[1], a2 = bb[2];
    const float* hr = h4 + (size_t)row * 64;
#pragma unroll
    for (int k = 0; k < 64; ++k) {
        float h = hr[k];
        a0 = fmaf(h, w[k * 3 + 0], a0);
        a1 = fmaf(h, w[k * 3 + 1], a1);
        a2 = fmaf(h, w[k * 3 + 2], a2);
    }
    float m  = fmaxf(a0, fmaxf(a1, a2));
    float e0 = expf(a0 - m), e1 = expf(a1 - m), e2 = expf(a2 - m);
    float inv = 1.0f / (e0 + e1 + e2);
    out[row * 3 + 0] = e0 * inv;
    out[row * 3 + 1] = e1 * inv;
    out[row * 3 + 2] = e2 * inv;
}

// ---------------------------------------------------------------------------
// Launch. Workspace layout (bf16 path):
//   Eb   @ 0                : 102,400,000 B  (bf16 table)
//   act  @ 102,400,000      : 16 MB ping-pong (sent/h2/h4 | h1/h3)
// ---------------------------------------------------------------------------
extern "C" void kernel_launch(void* const* d_in, const int* in_sizes, int n_in,
                              void* d_out, int out_size, void* d_ws,
                              size_t ws_size, hipStream_t stream)
{
    const int*   inputs = (const int*)d_in[0];
    const float* E  = (const float*)d_in[1];
    const float* W1 = (const float*)d_in[2];
    const float* b1 = (const float*)d_in[3];
    const float* W2 = (const float*)d_in[4];
    const float* b2 = (const float*)d_in[5];
    const float* W3 = (const float*)d_in[6];
    const float* b3 = (const float*)d_in[7];
    const float* W4 = (const float*)d_in[8];
    const float* b4 = (const float*)d_in[9];
    const float* W5 = (const float*)d_in[10];
    const float* b5 = (const float*)d_in[11];

    const size_t ebBytes = (size_t)VOCAB * EMB * 2;          // 102,400,000
    const size_t actBytes = 16ull * 1024 * 1024;
    const bool bf16path = ws_size >= ebBytes + actBytes;

    unsigned int* Eb = (unsigned int*)d_ws;
    float* act = bf16path ? (float*)((char*)d_ws + ebBytes) : (float*)d_ws;

    float* sent = act;
    float* h1   = act + 2097152;
    float* h2   = act;
    float* h3   = act + 2097152;
    float* h4   = act;
    float* out  = (float*)d_out;

    if (bf16path) {
        convert_E_bf16<<<2048, 256, 0, stream>>>(E, Eb, VOCAB * EMB / 8);
        embed_mean_bf16<<<BATCH, 256, 0, stream>>>(inputs, Eb, sent);
    } else {
        embed_mean_kernel<<<BATCH, 256, 0, stream>>>(inputs, E, sent);
    }
    gemm_bias_relu<512, 512><<<dim3(BATCH / 64, 512 / 64), 256, 0, stream>>>(
        sent, W1, b1, h1);
    gemm_bias_relu<256, 512><<<dim3(BATCH / 64, 256 / 64), 256, 0, stream>>>(
        h1, W2, b2, h2);
    gemm_bias_relu<128, 256><<<dim3(BATCH / 64, 128 / 64), 256, 0, stream>>>(
        h2, W3, b3, h3);
    gemm_bias_relu<64, 128><<<dim3(BATCH / 64, 64 / 64), 256, 0, stream>>>(
        h3, W4, b4, h4);
    final_softmax_kernel<<<BATCH / 256, 256, 0, stream>>>(h4, W5, b5, out);
}

// Round 3
// 223.352 us; speedup vs baseline: 1.4446x; 1.2216x over previous
//
#include <hip/hip_runtime.h>
#include <hip/hip_bf16.h>
#include <math.h>

#define BATCH 4096
#define SEQ 200
#define EMB 512
#define VOCAB 100000

typedef __attribute__((ext_vector_type(8))) short bf16x8;
typedef __attribute__((ext_vector_type(4))) float f32x4;

// ---------------------------------------------------------------------------
// bf16 helpers (RNE float->bf16; cheap bf16->float via bit ops)
// ---------------------------------------------------------------------------
__device__ inline unsigned int f2bf(float f) {
    unsigned int u = __float_as_uint(f);
    return (u + 0x7FFFu + ((u >> 16) & 1u)) >> 16;
}
__device__ inline unsigned int pack2(float lo, float hi) {
    return f2bf(lo) | (f2bf(hi) << 16);
}
__device__ inline float bflo(unsigned int u) { return __uint_as_float(u << 16); }
__device__ inline float bfhi(unsigned int u) { return __uint_as_float(u & 0xFFFF0000u); }

// ---------------------------------------------------------------------------
// Kernel 0a: convert E (fp32 [VOCAB x EMB]) -> bf16 table.
// ---------------------------------------------------------------------------
__global__ __launch_bounds__(256) void convert_E_bf16(
    const float* __restrict__ E, unsigned int* __restrict__ Eb4, int n8)
{
    const int stride = gridDim.x * 256;
    for (int i = blockIdx.x * 256 + threadIdx.x; i < n8; i += stride) {
        const float4* p = reinterpret_cast<const float4*>(E) + (size_t)i * 2;
        float4 a = p[0], b = p[1];
        uint4 o;
        o.x = pack2(a.x, a.y);
        o.y = pack2(a.z, a.w);
        o.z = pack2(b.x, b.y);
        o.w = pack2(b.z, b.w);
        reinterpret_cast<uint4*>(Eb4)[i] = o;
    }
}

// ---------------------------------------------------------------------------
// Kernel 0b: W [K x N] fp32 -> WT [N x K] bf16 (transpose via LDS 32x32 tile).
// block 256 = 32x8, grid (N/32, K/32).
// ---------------------------------------------------------------------------
__global__ __launch_bounds__(256) void convert_WT_bf16(
    const float* __restrict__ W, short* __restrict__ WT, int K, int N)
{
    __shared__ float lds[32][33];
    const int tx = threadIdx.x & 31;
    const int ty = threadIdx.x >> 5;  // 0..7
    const int n0 = blockIdx.x * 32;
    const int k0 = blockIdx.y * 32;
#pragma unroll
    for (int i = 0; i < 4; ++i)
        lds[ty + 8 * i][tx] = W[(size_t)(k0 + ty + 8 * i) * N + n0 + tx];
    __syncthreads();
#pragma unroll
    for (int i = 0; i < 4; ++i)
        WT[(size_t)(n0 + ty + 8 * i) * K + k0 + tx] =
            (short)f2bf(lds[tx][ty + 8 * i]);
}

// ---------------------------------------------------------------------------
// Kernel 1a: embedding bag from bf16 table -> bf16 sent. One block per batch
// row, 4 waves; each wave reads whole 1KB rows (64 lanes x 16B); fp32 acc.
// ---------------------------------------------------------------------------
__global__ __launch_bounds__(256) void embed_mean_bf16(
    const int* __restrict__ idx, const unsigned int* __restrict__ Eb,
    unsigned int* __restrict__ sentB)
{
    __shared__ int sIdx[SEQ];
    __shared__ float red[3 * 512];
    const int b = blockIdx.x;
    const int t = threadIdx.x;
    if (t < SEQ) sIdx[t] = idx[b * SEQ + t];
    __syncthreads();

    const int g = t >> 6;
    const int lane = t & 63;
    float acc[8] = {};
    for (int s = g; s < SEQ; s += 4) {
        const uint4* row =
            reinterpret_cast<const uint4*>(Eb + (size_t)sIdx[s] * (EMB / 2));
        uint4 v = row[lane];
        acc[0] += bflo(v.x); acc[1] += bfhi(v.x);
        acc[2] += bflo(v.y); acc[3] += bfhi(v.y);
        acc[4] += bflo(v.z); acc[5] += bfhi(v.z);
        acc[6] += bflo(v.w); acc[7] += bfhi(v.w);
    }
    if (g) {
        float4* r = reinterpret_cast<float4*>(&red[(g - 1) * 512 + lane * 8]);
        r[0] = make_float4(acc[0], acc[1], acc[2], acc[3]);
        r[1] = make_float4(acc[4], acc[5], acc[6], acc[7]);
    }
    __syncthreads();
    if (g == 0) {
        const float sc = 1.0f / (float)SEQ;
        float o[8];
#pragma unroll
        for (int j = 0; j < 8; ++j)
            o[j] = (acc[j] + red[0 * 512 + lane * 8 + j] +
                    red[1 * 512 + lane * 8 + j] + red[2 * 512 + lane * 8 + j]) * sc;
        uint4 pk;
        pk.x = pack2(o[0], o[1]);
        pk.y = pack2(o[2], o[3]);
        pk.z = pack2(o[4], o[5]);
        pk.w = pack2(o[6], o[7]);
        reinterpret_cast<uint4*>(sentB + (size_t)b * 256)[lane] = pk;
    }
}

// ---------------------------------------------------------------------------
// Kernel 1b (fallback fp32 gather)
// ---------------------------------------------------------------------------
__global__ __launch_bounds__(256) void embed_mean_kernel(
    const int* __restrict__ idx, const float* __restrict__ E,
    float* __restrict__ sent)
{
    __shared__ int sIdx[SEQ];
    __shared__ float4 red[128];
    const int b = blockIdx.x;
    const int t = threadIdx.x;
    if (t < SEQ) sIdx[t] = idx[b * SEQ + t];
    __syncthreads();

    const int half = t >> 7;
    const int lane = t & 127;
    float4 acc = make_float4(0.f, 0.f, 0.f, 0.f);
    for (int s = half; s < SEQ; s += 2) {
        const float4* row =
            reinterpret_cast<const float4*>(E + (size_t)sIdx[s] * EMB);
        float4 v = row[lane];
        acc.x += v.x; acc.y += v.y; acc.z += v.z; acc.w += v.w;
    }
    if (half == 1) red[lane] = acc;
    __syncthreads();
    if (half == 0) {
        float4 o = red[lane];
        const float sc = 1.0f / (float)SEQ;
        float4 r;
        r.x = (acc.x + o.x) * sc;
        r.y = (acc.y + o.y) * sc;
        r.z = (acc.z + o.z) * sc;
        r.w = (acc.w + o.w) * sc;
        reinterpret_cast<float4*>(sent + (size_t)b * EMB)[lane] = r;
    }
}

// ---------------------------------------------------------------------------
// Kernel 2a: bf16 MFMA GEMM, C = relu(A @ B + bias).
// A: bf16 [M][K] row-major. BT: bf16 [N][K] (pre-transposed weights).
// Tile: BM=128, BN=64, BK=32; 256 threads = 4 waves (2x2); wave = 64x32 out.
// LDS in fragment-contiguous 16B-slot layout: staging thread t writes slot t
// (linear, conflict-free); frag reads are base + lane (linear, conflict-free).
//   A slot(row,kg) = (row>>4)*64 + kg*16 + (row&15), row in [0,128), kg in [0,4)
//   lane l frag f: slot = (wr*4+f)*64 + (l>>4)*16 + (l&15)  [16B each]
// MFMA frag maps (16x16x32): A lane l: row=l&15, k=(l>>4)*8+j. B lane l:
// col=l&15, k=(l>>4)*8+j. D lane l: col=l&15, row=(l>>4)*4+reg.
// ---------------------------------------------------------------------------
template <int N, int K, bool OUT_BF16>
__global__ __launch_bounds__(256) void gemm_mfma_bias_relu(
    const short* __restrict__ A, const short* __restrict__ BT,
    const float* __restrict__ bias, void* __restrict__ C)
{
    constexpr int BM = 128, BN = 64, BK = 32;
    __shared__ float4 As[512];  // 128 rows x 4 kg-chunks
    __shared__ float4 Bs[256];  // 64 rows x 4 kg-chunks

    const int t = threadIdx.x;
    const int l = t & 63;
    const int w = t >> 6;
    const int wr = w >> 1;  // 0..1 : wave row block (64 rows)
    const int wc = w & 1;   // 0..1 : wave col block (32 cols)
    const int m0 = blockIdx.x * BM;
    const int n0 = blockIdx.y * BN;

    // staging coords: thread t stages chunk (row=(t>>6)*16+(t&15), kg=(t>>4)&3)
    const int srow = (t >> 6) * 16 + (t & 15);
    const int skg = (t >> 4) & 3;

    f32x4 acc[4][2] = {};

    for (int kt = 0; kt < K; kt += BK) {
        const float4 a0 = *reinterpret_cast<const float4*>(
            A + (size_t)(m0 + srow) * K + kt + skg * 8);
        const float4 a1 = *reinterpret_cast<const float4*>(
            A + (size_t)(m0 + srow + 64) * K + kt + skg * 8);
        const float4 b0 = *reinterpret_cast<const float4*>(
            BT + (size_t)(n0 + srow) * K + kt + skg * 8);
        __syncthreads();
        As[t] = a0;
        As[t + 256] = a1;
        Bs[t] = b0;
        __syncthreads();

        bf16x8 afr[4], bfr[2];
#pragma unroll
        for (int f = 0; f < 4; ++f)
            afr[f] = *reinterpret_cast<const bf16x8*>(
                &As[(wr * 4 + f) * 64 + (l >> 4) * 16 + (l & 15)]);
#pragma unroll
        for (int g = 0; g < 2; ++g)
            bfr[g] = *reinterpret_cast<const bf16x8*>(
                &Bs[(wc * 2 + g) * 64 + (l >> 4) * 16 + (l & 15)]);
#pragma unroll
        for (int f = 0; f < 4; ++f)
#pragma unroll
            for (int g = 0; g < 2; ++g)
                acc[f][g] = __builtin_amdgcn_mfma_f32_16x16x32_bf16(
                    afr[f], bfr[g], acc[f][g], 0, 0, 0);
    }

#pragma unroll
    for (int g = 0; g < 2; ++g) {
        const int col = n0 + wc * 32 + g * 16 + (l & 15);
        const float bv = bias[col];
#pragma unroll
        for (int f = 0; f < 4; ++f) {
#pragma unroll
            for (int r = 0; r < 4; ++r) {
                const int row = m0 + wr * 64 + f * 16 + (l >> 4) * 4 + r;
                const float v = fmaxf(acc[f][g][r] + bv, 0.f);
                if (OUT_BF16)
                    ((short*)C)[(size_t)row * N + col] = (short)f2bf(v);
                else
                    ((float*)C)[(size_t)row * N + col] = v;
            }
        }
    }
}

// ---------------------------------------------------------------------------
// Kernel 2b: fp32 tiled GEMM, C = relu(A @ W + bias). (L3/L4 + fallback)
// ---------------------------------------------------------------------------
template <int N, int K>
__global__ __launch_bounds__(256) void gemm_bias_relu(
    const float* __restrict__ A, const float* __restrict__ W,
    const float* __restrict__ bias, float* __restrict__ C)
{
    constexpr int BM = 64, BN = 64, BK = 16, LDT = 68;
    __shared__ float As[BK][LDT];
    __shared__ float Bs[BK][LDT];

    const int t = threadIdx.x;
    const int m0 = blockIdx.x * BM;
    const int n0 = blockIdx.y * BN;

    const int arow = t >> 2;
    const int acg  = (t & 3) * 4;
    const int brow = t >> 4;
    const int bcg  = (t & 15) * 4;

    const int tr = (t >> 4) * 4;
    const int tc = (t & 15) * 4;

    float acc[4][4] = {};

    for (int kt = 0; kt < K; kt += BK) {
        float4 av = *reinterpret_cast<const float4*>(
            &A[(size_t)(m0 + arow) * K + kt + acg]);
        float4 bv = *reinterpret_cast<const float4*>(
            &W[(size_t)(kt + brow) * N + n0 + bcg]);
        __syncthreads();
        As[acg + 0][arow] = av.x;
        As[acg + 1][arow] = av.y;
        As[acg + 2][arow] = av.z;
        As[acg + 3][arow] = av.w;
        *reinterpret_cast<float4*>(&Bs[brow][bcg]) = bv;
        __syncthreads();
#pragma unroll
        for (int kk = 0; kk < BK; ++kk) {
            float4 a4 = *reinterpret_cast<const float4*>(&As[kk][tr]);
            float4 b4 = *reinterpret_cast<const float4*>(&Bs[kk][tc]);
            float aa[4] = {a4.x, a4.y, a4.z, a4.w};
            float bb[4] = {b4.x, b4.y, b4.z, b4.w};
#pragma unroll
            for (int i = 0; i < 4; ++i)
#pragma unroll
                for (int j = 0; j < 4; ++j)
                    acc[i][j] = fmaf(aa[i], bb[j], acc[i][j]);
        }
    }

    float4 bias4 = *reinterpret_cast<const float4*>(&bias[n0 + tc]);
    float bb[4] = {bias4.x, bias4.y, bias4.z, bias4.w};
#pragma unroll
    for (int i = 0; i < 4; ++i) {
        float4 r;
        r.x = fmaxf(acc[i][0] + bb[0], 0.f);
        r.y = fmaxf(acc[i][1] + bb[1], 0.f);
        r.z = fmaxf(acc[i][2] + bb[2], 0.f);
        r.w = fmaxf(acc[i][3] + bb[3], 0.f);
        *reinterpret_cast<float4*>(&C[(size_t)(m0 + tr + i) * N + n0 + tc]) = r;
    }
}

// ---------------------------------------------------------------------------
// Kernel 3: final layer (K=64, N=3) + softmax. One thread per batch row.
// ---------------------------------------------------------------------------
__global__ __launch_bounds__(256) void final_softmax_kernel(
    const float* __restrict__ h4, const float* __restrict__ W5,
    const float* __restrict__ b5, float* __restrict__ out)
{
    __shared__ float w[64 * 3];
    __shared__ float bb[3];
    const int t = threadIdx.x;
    if (t < 192) w[t] = W5[t];
    if (t < 3) bb[t] = b5[t];
    __syncthreads();

    const int row = blockIdx.x * 256 + t;
    float a0 = bb[0], a1 = bb[1], a2 = bb[2];
    const float* hr = h4 + (size_t)row * 64;
#pragma unroll
    for (int k = 0; k < 64; ++k) {
        float h = hr[k];
        a0 = fmaf(h, w[k * 3 + 0], a0);
        a1 = fmaf(h, w[k * 3 + 1], a1);
        a2 = fmaf(h, w[k * 3 + 2], a2);
    }
    float m  = fmaxf(a0, fmaxf(a1, a2));
    float e0 = expf(a0 - m), e1 = expf(a1 - m), e2 = expf(a2 - m);
    float inv = 1.0f / (e0 + e1 + e2);
    out[row * 3 + 0] = e0 * inv;
    out[row * 3 + 1] = e1 * inv;
    out[row * 3 + 2] = e2 * inv;
}

// ---------------------------------------------------------------------------
// Workspace layout (bf16 path), bytes:
//   Eb    @ 0           : 102,400,000  (bf16 E)
//   W1T   @ 102,400,000 :     524,288  (bf16 [512][512])
//   W2T   @ 102,924,288 :     262,144  (bf16 [256][512])
//   sentB @ 103,186,432 :   4,194,304  (bf16 [4096][512])
//   h1B   @ 107,380,736 :   4,194,304  (bf16 [4096][512])
//   h2    @ 111,575,040 :   4,194,304  (f32  [4096][256])
//   h3    @ 115,769,344 :   2,097,152  (f32  [4096][128])
//   h4    @ 117,866,496 :   1,048,576  (f32  [4096][64])   total 118,915,072
// ---------------------------------------------------------------------------
extern "C" void kernel_launch(void* const* d_in, const int* in_sizes, int n_in,
                              void* d_out, int out_size, void* d_ws,
                              size_t ws_size, hipStream_t stream)
{
    const int*   inputs = (const int*)d_in[0];
    const float* E  = (const float*)d_in[1];
    const float* W1 = (const float*)d_in[2];
    const float* b1 = (const float*)d_in[3];
    const float* W2 = (const float*)d_in[4];
    const float* b2 = (const float*)d_in[5];
    const float* W3 = (const float*)d_in[6];
    const float* b3 = (const float*)d_in[7];
    const float* W4 = (const float*)d_in[8];
    const float* b4 = (const float*)d_in[9];
    const float* W5 = (const float*)d_in[10];
    const float* b5 = (const float*)d_in[11];
    float* out = (float*)d_out;

    const size_t ebBytes = (size_t)VOCAB * EMB * 2;  // 102,400,000
    const size_t needed = ebBytes + 524288 + 262144 + 3 * 4194304 + 2097152 + 1048576;

    if (ws_size >= needed) {
        char* p = (char*)d_ws;
        unsigned int* Eb   = (unsigned int*)p;
        short*        W1T  = (short*)(p + ebBytes);
        short*        W2T  = (short*)(p + ebBytes + 524288);
        unsigned int* sentB = (unsigned int*)(p + ebBytes + 786432);
        short*        h1B  = (short*)(p + ebBytes + 786432 + 4194304);
        float*        h2   = (float*)(p + ebBytes + 786432 + 2 * 4194304);
        float*        h3   = (float*)(p + ebBytes + 786432 + 3 * 4194304);
        float*        h4   = (float*)(p + ebBytes + 786432 + 3 * 4194304 + 2097152);

        convert_E_bf16<<<2048, 256, 0, stream>>>(E, Eb, VOCAB * EMB / 8);
        convert_WT_bf16<<<dim3(512 / 32, 512 / 32), 256, 0, stream>>>(W1, W1T, 512, 512);
        convert_WT_bf16<<<dim3(256 / 32, 512 / 32), 256, 0, stream>>>(W2, W2T, 512, 256);
        embed_mean_bf16<<<BATCH, 256, 0, stream>>>(inputs, Eb, sentB);

        gemm_mfma_bias_relu<512, 512, true>
            <<<dim3(BATCH / 128, 512 / 64), 256, 0, stream>>>(
                (const short*)sentB, W1T, b1, (void*)h1B);
        gemm_mfma_bias_relu<256, 512, false>
            <<<dim3(BATCH / 128, 256 / 64), 256, 0, stream>>>(
                h1B, W2T, b2, (void*)h2);
        gemm_bias_relu<128, 256><<<dim3(BATCH / 64, 2), 256, 0, stream>>>(
            h2, W3, b3, h3);
        gemm_bias_relu<64, 128><<<dim3(BATCH / 64, 1), 256, 0, stream>>>(
            h3, W4, b4, h4);
        final_softmax_kernel<<<BATCH / 256, 256, 0, stream>>>(h4, W5, b5, out);
    } else {
        // fp32 fallback (small workspace)
        float* act  = (float*)d_ws;
        float* sent = act;
        float* h1   = act + 2097152;
        float* h2   = act;
        float* h3   = act + 2097152;
        float* h4   = act;
        embed_mean_kernel<<<BATCH, 256, 0, stream>>>(inputs, E, sent);
        gemm_bias_relu<512, 512><<<dim3(BATCH / 64, 8), 256, 0, stream>>>(
            sent, W1, b1, h1);
        gemm_bias_relu<256, 512><<<dim3(BATCH / 64, 4), 256, 0, stream>>>(
            h1, W2, b2, h2);
        gemm_bias_relu<128, 256><<<dim3(BATCH / 64, 2), 256, 0, stream>>>(
            h2, W3, b3, h3);
        gemm_bias_relu<64, 128><<<dim3(BATCH / 64, 1), 256, 0, stream>>>(
            h3, W4, b4, h4);
        final_softmax_kernel<<<BATCH / 256, 256, 0, stream>>>(h4, W5, b5, out);
    }
}